// Round 13
// baseline (2685.977 us; speedup 1.0000x reference)
//
#include <hip/hip_runtime.h>
#include <hip/hip_bf16.h>

// GRU-GAN generator, MI355X. Round 13 — two independent tiles per block.
// B=512, H=64, S=2048, F=32. 16 blocks x 1024 threads (16 waves, 4/EU).
// Waves 0-7: batch tile A (rows row0..row0+15); waves 8-15: tile B (+16).
// Each tile runs R8's combined-role 2-barrier pipeline (best verified):
//   all 8 tile-waves: gates (dir=tw>>2, cb=tw&3), pinned frags, merged-rcp;
//   tile-waves 0-3: + latent (W2); tile-waves 6-7: + out-proj (W2) + y store.
// R13 rationale: R8/R9/R11 flatlined ~1760cy/step with per-SIMD issue ~880cy
// (VALUBusy ~50% active-normalized) — the rest is the recurrence dependency
// chain with NOTHING independent to issue (all waves barrier-coupled to one
// recurrence; R12 with fewer waves regressed). Co-locating a second
// independent recurrence fills the stalls: per-SIMD ~1760cy issue per PAIR
// of tile-steps -> ~2x per-CU throughput. Shared barriers, identical counts.
// Role-guarded weight loads to fit the 128-VGPR cap (4 waves/EU).

#define NBATCH 512
#define NH 64
#define NS 2048
#define NF 32
#define MROW 16
#define LDH 72    // padded LDS row stride (shorts): 144 B

typedef short s16x8 __attribute__((ext_vector_type(8)));
typedef float f32x4 __attribute__((ext_vector_type(4)));

#define MFMA(a, b, c) __builtin_amdgcn_mfma_f32_16x16x32_bf16((a), (b), (c), 0, 0, 0)

#define NLOG2E  (-1.4426950408889634f)
#define N2LOG2E (-2.8853900817779268f)

#define PIN(x) __asm__("" : "+v"(x))

// barrier that waits only on LDS (no vmcnt drain like __syncthreads)
__device__ __forceinline__ void bar_lds() {
    __asm__ volatile("s_waitcnt lgkmcnt(0)\n\ts_barrier" ::: "memory");
}

__device__ __forceinline__ short f2bf(float f) {
    return (short)((__float_as_uint(f) + 0x8000u) >> 16);
}

__device__ __forceinline__ f32x4 v_exp2(f32x4 a) {
    f32x4 r;
#pragma unroll
    for (int i = 0; i < 4; ++i) r[i] = __builtin_amdgcn_exp2f(a[i]);
    return r;
}

__device__ __forceinline__ f32x4 v_rcp(f32x4 a) {
    f32x4 r;
#pragma unroll
    for (int i = 0; i < 4; ++i) r[i] = __builtin_amdgcn_rcpf(a[i]);
    return r;
}

__device__ __forceinline__ f32x4 v_lk(f32x4 a) {
    f32x4 b = a * 0.01f;
    f32x4 r;
#pragma unroll
    for (int i = 0; i < 4; ++i) r[i] = fmaxf(a[i], b[i]);
    return r;
}

__device__ __forceinline__ f32x4 v_sigm(f32x4 a) {
    return v_rcp(v_exp2(a * NLOG2E) + 1.0f);
}

__device__ __forceinline__ int2 pk4bf(f32x4 v) {
    union { __hip_bfloat162 b; int i; } lo, hi;
    float2 a; a.x = v[0]; a.y = v[1];
    float2 b; b.x = v[2]; b.y = v[3];
    lo.b = __float22bfloat162_rn(a);
    hi.b = __float22bfloat162_rn(b);
    int2 r; r.x = lo.i; r.y = hi.i;
    return r;
}

__device__ __forceinline__ s16x8 bfragW(const float* __restrict__ W, int ldk,
                                        int row, int kf, int quad) {
    const float* p = W + (size_t)row * ldk + kf * 32 + quad * 8;
    s16x8 r;
#pragma unroll
    for (int i = 0; i < 8; ++i) r[i] = f2bf(p[i]);
    return r;
}

__device__ __forceinline__ f32x4 bias4(const float* __restrict__ p) {
    const float4 v = *(const float4*)p;
    f32x4 r = {v.x, v.y, v.z, v.w};
    return r;
}

__global__ __launch_bounds__(1024)
__attribute__((amdgpu_waves_per_eu(4, 4)))
void grugan_kernel(const float* __restrict__ noise,
                   const float* __restrict__ Wihf, const float* __restrict__ Whhf,
                   const float* __restrict__ bihf, const float* __restrict__ bhhf,
                   const float* __restrict__ Wihb, const float* __restrict__ Whhb,
                   const float* __restrict__ bihb, const float* __restrict__ bhhb,
                   const float* __restrict__ Wlat, const float* __restrict__ blat,
                   const float* __restrict__ Wout, const float* __restrict__ bout,
                   float* __restrict__ out)
{
    __shared__ __align__(16) short Xs[2][2][MROW][LDH];    // [tile][buf]
    __shared__ __align__(16) short X2s[2][2][MROW][LDH];   // [tile][buf]
    __shared__ __align__(16) short Hs[2][2][2][MROW][LDH]; // [tile][buf][dir]

    const int tid  = threadIdx.x;
    const int wave = tid >> 6;
    const int lane = tid & 63;
    const int n    = lane & 15;   // batch row within tile
    const int quad = lane >> 4;
    const int tile = wave >> 3;   // 0 = tile A, 1 = tile B
    const int tw   = wave & 7;    // wave-within-tile
    const int row0 = blockIdx.x * (2 * MROW) + tile * MROW;

    // per-tile LDS bases
    short (* const Xst)[MROW][LDH]  = Xs[tile];
    short (* const X2st)[MROW][LDH] = X2s[tile];
    short (* const Hst)[2][MROW][LDH] = Hs[tile];

    // ---- gate role (all waves) ----
    const int dir  = tw >> 2;
    const int cb   = tw & 3;
    const int jrow = cb * 16 + n;
    const int jq   = cb * 16 + quad * 4;
    const float* Wih = dir ? Wihb : Wihf;
    const float* Whh = dir ? Whhb : Whhf;
    const float* bih = dir ? bihb : bihf;
    const float* bhh = dir ? bhhb : bhhf;

    s16x8 wir0 = bfragW(Wih, NH,   0 + jrow, 0, quad);
    s16x8 wir1 = bfragW(Wih, NH,   0 + jrow, 1, quad);
    s16x8 wiz0 = bfragW(Wih, NH,  64 + jrow, 0, quad);
    s16x8 wiz1 = bfragW(Wih, NH,  64 + jrow, 1, quad);
    s16x8 win0 = bfragW(Wih, NH, 128 + jrow, 0, quad);
    s16x8 win1 = bfragW(Wih, NH, 128 + jrow, 1, quad);
    s16x8 whr0 = bfragW(Whh, NH,   0 + jrow, 0, quad);
    s16x8 whr1 = bfragW(Whh, NH,   0 + jrow, 1, quad);
    s16x8 whz0 = bfragW(Whh, NH,  64 + jrow, 0, quad);
    s16x8 whz1 = bfragW(Whh, NH,  64 + jrow, 1, quad);
    s16x8 whn0 = bfragW(Whh, NH, 128 + jrow, 0, quad);
    s16x8 whn1 = bfragW(Whh, NH, 128 + jrow, 1, quad);
    f32x4 initR, initZ;
    {
        f32x4 a = bias4(&bih[jq]),      b = bias4(&bhh[jq]);
        initR = a + b;
        f32x4 c = bias4(&bih[64 + jq]), d = bias4(&bhh[64 + jq]);
        initZ = c + d;
    }
    f32x4 initN1 = bias4(&bih[128 + jq]);
    f32x4 initN2 = bias4(&bhh[128 + jq]);
    PIN(wir0); PIN(wir1); PIN(wiz0); PIN(wiz1); PIN(win0); PIN(win1);
    PIN(whr0); PIN(whr1); PIN(whz0); PIN(whz1); PIN(whn0); PIN(whn1);
    PIN(initR); PIN(initZ); PIN(initN1); PIN(initN2);

    // ---- latent role (tw 0-3 only; guarded to save VGPRs elsewhere) ----
    const int nq = (tw & 3) * 16 + quad * 4;
    s16x8 wl0 = {}, wl1 = {}, wl2 = {}, wl3 = {};
    f32x4 initL = {0.f, 0.f, 0.f, 0.f};
    if (tw < 4) {
        wl0 = bfragW(Wlat, 2 * NH, (tw & 3) * 16 + n, 0, quad);
        wl1 = bfragW(Wlat, 2 * NH, (tw & 3) * 16 + n, 1, quad);
        wl2 = bfragW(Wlat, 2 * NH, (tw & 3) * 16 + n, 2, quad);
        wl3 = bfragW(Wlat, 2 * NH, (tw & 3) * 16 + n, 3, quad);
        initL = bias4(&blat[(tw & 3) * 16 + quad * 4]);
        PIN(wl0); PIN(wl1); PIN(wl2); PIN(wl3); PIN(initL);
    }

    // ---- out-proj role (tw 6,7 only) ----
    const int f0 = (tw & 1) * 16;
    s16x8 wo0 = {}, wo1 = {};
    f32x4 initO = {0.f, 0.f, 0.f, 0.f};
    if (tw >= 6) {
        wo0 = bfragW(Wout, NH, f0 + n, 0, quad);
        wo1 = bfragW(Wout, NH, f0 + n, 1, quad);
        initO = bias4(&bout[f0 + quad * 4]);
        PIN(wo0); PIN(wo1); PIN(initO);
    }
    float* const orow = out + (size_t)(row0 + n) * (NS * NF) + f0 + quad * 4;

    // ---- state init: x(0) = 0 (both tiles/bufs); h(0) = noise ----
    for (int idx = tid; idx < 2 * 2 * MROW * LDH; idx += 1024)
        (&Xs[0][0][0][0])[idx] = 0;
    f32x4 hreg;
    {
        const float4 nz = *(const float4*)&noise[(size_t)(row0 + n) * NH + jq];
        hreg[0] = nz.x; hreg[1] = nz.y; hreg[2] = nz.z; hreg[3] = nz.w;
        *(int2*)&Hst[0][dir][n][jq] = pk4bf(hreg);
    }
    __syncthreads();

    // ---- prologue: gh accumulators for t=0 from h(0) ----
    f32x4 accR, accZ, accN2;
    {
        s16x8 ha0 = *(const s16x8*)&Hst[0][dir][n][quad * 8];
        s16x8 ha1 = *(const s16x8*)&Hst[0][dir][n][32 + quad * 8];
        accR  = MFMA(whr0, ha0, initR);  accR  = MFMA(whr1, ha1, accR);
        accZ  = MFMA(whz0, ha0, initZ);  accZ  = MFMA(whz1, ha1, accZ);
        accN2 = MFMA(whn0, ha0, initN2); accN2 = MFMA(whn1, ha1, accN2);
    }

    f32x4 yv = {0.f, 0.f, 0.f, 0.f};   // pending y (tw 6,7)

#define STEP(HB, T) do {                                                        \
    if ((T) >= 2 && tw >= 6)                                                    \
        *(f32x4*)(orow + (size_t)((T) - 2) * NF) = yv;                          \
    {                                                                           \
        s16x8 xa0 = *(const s16x8*)&Xst[HB][n][quad * 8];                       \
        s16x8 xa1 = *(const s16x8*)&Xst[HB][n][32 + quad * 8];                  \
        accR = MFMA(wir0, xa0, accR);   accR = MFMA(wir1, xa1, accR);           \
        accZ = MFMA(wiz0, xa0, accZ);   accZ = MFMA(wiz1, xa1, accZ);           \
        f32x4 accN1 = MFMA(win0, xa0, initN1);                                  \
        accN1 = MFMA(win1, xa1, accN1);                                         \
        f32x4 eR = v_exp2(accR * NLOG2E);                                       \
        f32x4 rr = v_rcp(eR + 1.0f);                                            \
        f32x4 u  = accN1 + rr * accN2;                                          \
        f32x4 eU = v_exp2(u * N2LOG2E);                                         \
        f32x4 eZ = v_exp2(accZ * NLOG2E);                                       \
        f32x4 numer = (eZ + hreg) + eU * (hreg - eZ);                           \
        f32x4 denom = (eU + 1.0f) * (eZ + 1.0f);                                \
        hreg = numer * v_rcp(denom);                                            \
        *(int2*)&Hst[(HB) ^ 1][dir][n][jq] = pk4bf(hreg);                       \
    }                                                                           \
    bar_lds();  /* b1: H(t+1) visible */                                        \
    {                                                                           \
        s16x8 ha0 = *(const s16x8*)&Hst[(HB) ^ 1][dir][n][quad * 8];            \
        s16x8 ha1 = *(const s16x8*)&Hst[(HB) ^ 1][dir][n][32 + quad * 8];       \
        if (tw < 4) {                                                           \
            /* latent (dir==0 here, so ha == fwd h) */                          \
            s16x8 ba0 = *(const s16x8*)&Hst[(HB) ^ 1][1][n][quad * 8];          \
            s16x8 ba1 = *(const s16x8*)&Hst[(HB) ^ 1][1][n][32 + quad * 8];     \
            f32x4 c1 = MFMA(wl0, ha0, initL);                                   \
            c1 = MFMA(wl1, ha1, c1);                                            \
            f32x4 c2 = MFMA(wl2, ba0, c1);                                      \
            c2 = MFMA(wl3, ba1, c2);                                            \
            f32x4 la = v_lk(c2);                                                \
            *(int2*)&Xst[(HB) ^ 1][n][nq]  = pk4bf(la);                         \
            *(int2*)&X2st[(HB) ^ 1][n][nq] = pk4bf(v_lk(la));                   \
        } else if (tw >= 6 && (T) >= 1) {                                       \
            s16x8 p0 = *(const s16x8*)&X2st[HB][n][quad * 8];                   \
            s16x8 p1 = *(const s16x8*)&X2st[HB][n][32 + quad * 8];              \
            f32x4 po = MFMA(wo0, p0, initO);                                    \
            po = MFMA(wo1, p1, po);                                             \
            yv = v_sigm(po);                                                    \
        }                                                                       \
        accR  = MFMA(whr0, ha0, initR);  accR  = MFMA(whr1, ha1, accR);         \
        accZ  = MFMA(whz0, ha0, initZ);  accZ  = MFMA(whz1, ha1, accZ);         \
        accN2 = MFMA(whn0, ha0, initN2); accN2 = MFMA(whn1, ha1, accN2);        \
    }                                                                           \
    bar_lds();  /* b2: x(t+1) visible */                                        \
} while (0)

    for (int t = 0; t < NS; t += 2) {
        STEP(0, t);
        STEP(1, t + 1);
    }
#undef STEP

    // ---- epilogue (tw 6,7 of each tile) ----
    if (tw >= 6) {
        *(f32x4*)(orow + (size_t)(NS - 2) * NF) = yv;       // y(NS-2)
        s16x8 p0 = *(const s16x8*)&X2st[0][n][quad * 8];    // lk(x(NS)) -> y(NS-1)
        s16x8 p1 = *(const s16x8*)&X2st[0][n][32 + quad * 8];
        f32x4 po = MFMA(wo0, p0, initO);
        po = MFMA(wo1, p1, po);
        *(f32x4*)(orow + (size_t)(NS - 1) * NF) = v_sigm(po);
    }
}

extern "C" void kernel_launch(void* const* d_in, const int* in_sizes, int n_in,
                              void* d_out, int out_size, void* d_ws, size_t ws_size,
                              hipStream_t stream) {
    const float* noise = (const float*)d_in[0];
    const float* Wihf  = (const float*)d_in[1];
    const float* Whhf  = (const float*)d_in[2];
    const float* bihf  = (const float*)d_in[3];
    const float* bhhf  = (const float*)d_in[4];
    const float* Wihb  = (const float*)d_in[5];
    const float* Whhb  = (const float*)d_in[6];
    const float* bihb  = (const float*)d_in[7];
    const float* bhhb  = (const float*)d_in[8];
    const float* Wlat  = (const float*)d_in[9];
    const float* blat  = (const float*)d_in[10];
    const float* Wout  = (const float*)d_in[11];
    const float* bout  = (const float*)d_in[12];

    grugan_kernel<<<dim3(NBATCH / (2 * MROW)), dim3(1024), 0, stream>>>(
        noise, Wihf, Whhf, bihf, bhhf, Wihb, Whhb, bihb, bhhb,
        Wlat, blat, Wout, bout, (float*)d_out);
}

// Round 14
// 2627.060 us; speedup vs baseline: 1.0224x; 1.0224x over previous
//
#include <hip/hip_runtime.h>
#include <hip/hip_bf16.h>

// GRU-GAN generator, MI355X. Round 14 — single-barrier redundant-latent (R10)
// rescued with register pinning (R11) + relaxed VGPR budget.
// B=512, H=64, S=2048, F=32. 32 blocks x 512 threads (8 waves, <=2/EU).
// Block = 16 batch rows (M=16 MFMA tile, transposed D[j][m] layout).
// Every wave: full latent (redundant, 16 frags) + its (dir, colblock) gates
// (12 frags); waves 0,1 also out-proj (2 frags). x(t+1) never crosses waves:
// D->A transpose via wave-local LDS scratch (in-order DS pipe, no barrier).
// ONE bar_lds per step (h handoff only).
// Why this wins (R13 evidence): issue ~880cy/SIMD/step + ~880 unhidden chain
// at 2 windows/step; this structure has 1 window (chain -~500cy) and 8 waves
// doing 28 MFMA each (issue ~620/SIMD). R10 failed ONLY on registers
// (VGPR capped 128 -> remat, FETCH 2850MB). Fixes: PIN on all 30 frags +
// 9 bias vectors (R11-proven to stop remat), waves_per_eu(1,2) -> cap 512.
// Falsifiers: VGPR_Count==128 or FETCH>=1300MB.

#define NBATCH 512
#define NH 64
#define NS 2048
#define NF 32
#define MROW 16
#define LDH 72    // padded LDS row stride (shorts): 144 B

typedef short s16x8 __attribute__((ext_vector_type(8)));
typedef float f32x4 __attribute__((ext_vector_type(4)));

#define MFMA(a, b, c) __builtin_amdgcn_mfma_f32_16x16x32_bf16((a), (b), (c), 0, 0, 0)

#define NLOG2E  (-1.4426950408889634f)
#define N2LOG2E (-2.8853900817779268f)

#define PIN(x) __asm__("" : "+v"(x))

// barrier that waits only on LDS (no vmcnt drain like __syncthreads)
__device__ __forceinline__ void bar_lds() {
    __asm__ volatile("s_waitcnt lgkmcnt(0)\n\ts_barrier" ::: "memory");
}

__device__ __forceinline__ short f2bf(float f) {
    return (short)((__float_as_uint(f) + 0x8000u) >> 16);
}

__device__ __forceinline__ f32x4 v_exp2(f32x4 a) {
    f32x4 r;
#pragma unroll
    for (int i = 0; i < 4; ++i) r[i] = __builtin_amdgcn_exp2f(a[i]);
    return r;
}

__device__ __forceinline__ f32x4 v_rcp(f32x4 a) {
    f32x4 r;
#pragma unroll
    for (int i = 0; i < 4; ++i) r[i] = __builtin_amdgcn_rcpf(a[i]);
    return r;
}

__device__ __forceinline__ f32x4 v_lk(f32x4 a) {
    f32x4 b = a * 0.01f;
    f32x4 r;
#pragma unroll
    for (int i = 0; i < 4; ++i) r[i] = fmaxf(a[i], b[i]);
    return r;
}

__device__ __forceinline__ f32x4 v_sigm(f32x4 a) {
    return v_rcp(v_exp2(a * NLOG2E) + 1.0f);
}

__device__ __forceinline__ int2 pk4bf(f32x4 v) {
    union { __hip_bfloat162 b; int i; } lo, hi;
    float2 a; a.x = v[0]; a.y = v[1];
    float2 b; b.x = v[2]; b.y = v[3];
    lo.b = __float22bfloat162_rn(a);
    hi.b = __float22bfloat162_rn(b);
    int2 r; r.x = lo.i; r.y = hi.i;
    return r;
}

// exact merged-rcp GRU update: one rcp, algebraically = sigmoid/tanh form
__device__ __forceinline__ f32x4 gru_up(f32x4 aR, f32x4 aZ, f32x4 aN1,
                                        f32x4 aN2, f32x4 h) {
    f32x4 eR = v_exp2(aR * NLOG2E);
    f32x4 rr = v_rcp(eR + 1.0f);
    f32x4 u  = aN1 + rr * aN2;
    f32x4 eU = v_exp2(u * N2LOG2E);
    f32x4 eZ = v_exp2(aZ * NLOG2E);
    f32x4 numer = (eZ + h) + eU * (h - eZ);
    f32x4 denom = (eU + 1.0f) * (eZ + 1.0f);
    return numer * v_rcp(denom);
}

__device__ __forceinline__ s16x8 bfragW(const float* __restrict__ W, int ldk,
                                        int row, int kf, int quad) {
    const float* p = W + (size_t)row * ldk + kf * 32 + quad * 8;
    s16x8 r;
#pragma unroll
    for (int i = 0; i < 8; ++i) r[i] = f2bf(p[i]);
    return r;
}

__device__ __forceinline__ f32x4 bias4(const float* __restrict__ p) {
    const float4 v = *(const float4*)p;
    f32x4 r = {v.x, v.y, v.z, v.w};
    return r;
}

__global__ __launch_bounds__(512)
__attribute__((amdgpu_waves_per_eu(1, 2)))
void grugan_kernel(const float* __restrict__ noise,
                   const float* __restrict__ Wihf, const float* __restrict__ Whhf,
                   const float* __restrict__ bihf, const float* __restrict__ bhhf,
                   const float* __restrict__ Wihb, const float* __restrict__ Whhb,
                   const float* __restrict__ bihb, const float* __restrict__ bhhb,
                   const float* __restrict__ Wlat, const float* __restrict__ blat,
                   const float* __restrict__ Wout, const float* __restrict__ bout,
                   float* __restrict__ out)
{
    __shared__ __align__(16) short Hs[2][2][MROW][LDH];   // [buf][dir][m][k]
    __shared__ __align__(16) short xscr[8][MROW][LDH];    // per-wave x scratch
    __shared__ __align__(16) short x2scr[2][MROW][LDH];   // waves 0,1: lk(x)

    const int tid  = threadIdx.x;
    const int wave = tid >> 6;
    const int lane = tid & 63;
    const int n    = lane & 15;   // batch row within tile
    const int quad = lane >> 4;
    const int row0 = blockIdx.x * MROW;

    const int dir  = wave >> 2;          // 0 fwd, 1 bwd
    const int cb   = wave & 3;           // 16-col block of hidden state
    const int jrow = cb * 16 + n;
    const int jq   = cb * 16 + quad * 4;
    const float* Wih = dir ? Wihb : Wihf;
    const float* Whh = dir ? Whhb : Whhf;
    const float* bih = dir ? bihb : bihf;
    const float* bhh = dir ? bhhb : bhhf;

    // ---- gate weight fragments (12) ----
    s16x8 wir0 = bfragW(Wih, NH,   0 + jrow, 0, quad);
    s16x8 wir1 = bfragW(Wih, NH,   0 + jrow, 1, quad);
    s16x8 wiz0 = bfragW(Wih, NH,  64 + jrow, 0, quad);
    s16x8 wiz1 = bfragW(Wih, NH,  64 + jrow, 1, quad);
    s16x8 win0 = bfragW(Wih, NH, 128 + jrow, 0, quad);
    s16x8 win1 = bfragW(Wih, NH, 128 + jrow, 1, quad);
    s16x8 whr0 = bfragW(Whh, NH,   0 + jrow, 0, quad);
    s16x8 whr1 = bfragW(Whh, NH,   0 + jrow, 1, quad);
    s16x8 whz0 = bfragW(Whh, NH,  64 + jrow, 0, quad);
    s16x8 whz1 = bfragW(Whh, NH,  64 + jrow, 1, quad);
    s16x8 whn0 = bfragW(Whh, NH, 128 + jrow, 0, quad);
    s16x8 whn1 = bfragW(Whh, NH, 128 + jrow, 1, quad);
    f32x4 initR, initZ;
    {
        f32x4 a = bias4(&bih[jq]),      b = bias4(&bhh[jq]);
        initR = a + b;
        f32x4 c = bias4(&bih[64 + jq]), d = bias4(&bhh[64 + jq]);
        initZ = c + d;
    }
    f32x4 initN1 = bias4(&bih[128 + jq]);
    f32x4 initN2 = bias4(&bhh[128 + jq]);
    PIN(wir0); PIN(wir1); PIN(wiz0); PIN(wiz1); PIN(win0); PIN(win1);
    PIN(whr0); PIN(whr1); PIN(whz0); PIN(whz1); PIN(whn0); PIN(whn1);
    PIN(initR); PIN(initZ); PIN(initN1); PIN(initN2);

    // ---- full latent weight set (16 frags) — every wave, redundant ----
    s16x8 wl00 = bfragW(Wlat, 2 * NH,  0 + n, 0, quad);
    s16x8 wl01 = bfragW(Wlat, 2 * NH,  0 + n, 1, quad);
    s16x8 wl02 = bfragW(Wlat, 2 * NH,  0 + n, 2, quad);
    s16x8 wl03 = bfragW(Wlat, 2 * NH,  0 + n, 3, quad);
    s16x8 wl10 = bfragW(Wlat, 2 * NH, 16 + n, 0, quad);
    s16x8 wl11 = bfragW(Wlat, 2 * NH, 16 + n, 1, quad);
    s16x8 wl12 = bfragW(Wlat, 2 * NH, 16 + n, 2, quad);
    s16x8 wl13 = bfragW(Wlat, 2 * NH, 16 + n, 3, quad);
    s16x8 wl20 = bfragW(Wlat, 2 * NH, 32 + n, 0, quad);
    s16x8 wl21 = bfragW(Wlat, 2 * NH, 32 + n, 1, quad);
    s16x8 wl22 = bfragW(Wlat, 2 * NH, 32 + n, 2, quad);
    s16x8 wl23 = bfragW(Wlat, 2 * NH, 32 + n, 3, quad);
    s16x8 wl30 = bfragW(Wlat, 2 * NH, 48 + n, 0, quad);
    s16x8 wl31 = bfragW(Wlat, 2 * NH, 48 + n, 1, quad);
    s16x8 wl32 = bfragW(Wlat, 2 * NH, 48 + n, 2, quad);
    s16x8 wl33 = bfragW(Wlat, 2 * NH, 48 + n, 3, quad);
    f32x4 bL0 = bias4(&blat[ 0 + quad * 4]);
    f32x4 bL1 = bias4(&blat[16 + quad * 4]);
    f32x4 bL2 = bias4(&blat[32 + quad * 4]);
    f32x4 bL3 = bias4(&blat[48 + quad * 4]);
    PIN(wl00); PIN(wl01); PIN(wl02); PIN(wl03);
    PIN(wl10); PIN(wl11); PIN(wl12); PIN(wl13);
    PIN(wl20); PIN(wl21); PIN(wl22); PIN(wl23);
    PIN(wl30); PIN(wl31); PIN(wl32); PIN(wl33);
    PIN(bL0); PIN(bL1); PIN(bL2); PIN(bL3);

    // ---- out-proj (waves 0,1 only; guarded) ----
    const int f0 = (wave & 1) * 16;
    s16x8 wo0 = {}, wo1 = {};
    f32x4 initO = {0.f, 0.f, 0.f, 0.f};
    if (wave < 2) {
        wo0 = bfragW(Wout, NH, f0 + n, 0, quad);
        wo1 = bfragW(Wout, NH, f0 + n, 1, quad);
        initO = bias4(&bout[f0 + quad * 4]);
        PIN(wo0); PIN(wo1); PIN(initO);
    }
    float* const orow = out + (size_t)(row0 + n) * (NS * NF) + f0 + quad * 4;

    const f32x4 Z4 = {0.f, 0.f, 0.f, 0.f};

    // ---- prologue: h(1) = G(x0=0, h0=noise) -> Hs[0] ----
    f32x4 hreg;
    {
        const float4 nz = *(const float4*)&noise[(size_t)(row0 + n) * NH + jq];
        hreg[0] = nz.x; hreg[1] = nz.y; hreg[2] = nz.z; hreg[3] = nz.w;
        s16x8 nf0 = bfragW(noise, NH, row0 + n, 0, quad);
        s16x8 nf1 = bfragW(noise, NH, row0 + n, 1, quad);
        f32x4 aR  = MFMA(whr0, nf0, initR);  aR  = MFMA(whr1, nf1, aR);
        f32x4 aZ  = MFMA(whz0, nf0, initZ);  aZ  = MFMA(whz1, nf1, aZ);
        f32x4 aN2 = MFMA(whn0, nf0, initN2); aN2 = MFMA(whn1, nf1, aN2);
        hreg = gru_up(aR, aZ, initN1, aN2, hreg);   // gi = 0 (x0 = 0)
        *(int2*)&Hs[0][dir][n][jq] = pk4bf(hreg);
    }
    __syncthreads();

#define WINDOW(HB, T) do {                                                      \
    /* h(T+1), both directions */                                               \
    s16x8 fa0 = *(const s16x8*)&Hs[HB][0][n][quad * 8];                         \
    s16x8 fa1 = *(const s16x8*)&Hs[HB][0][n][32 + quad * 8];                    \
    s16x8 ba0 = *(const s16x8*)&Hs[HB][1][n][quad * 8];                         \
    s16x8 ba1 = *(const s16x8*)&Hs[HB][1][n][32 + quad * 8];                    \
    /* full latent, redundant per wave: x(T+1) = ys[T] in D-layout */           \
    f32x4 c1, c2, la0, la1, la2, la3;                                           \
    c1 = MFMA(wl00, fa0, bL0); c1 = MFMA(wl01, fa1, c1);                        \
    c2 = MFMA(wl02, ba0, Z4);  c2 = MFMA(wl03, ba1, c2);                        \
    la0 = v_lk(c1 + c2);                                                        \
    c1 = MFMA(wl10, fa0, bL1); c1 = MFMA(wl11, fa1, c1);                        \
    c2 = MFMA(wl12, ba0, Z4);  c2 = MFMA(wl13, ba1, c2);                        \
    la1 = v_lk(c1 + c2);                                                        \
    c1 = MFMA(wl20, fa0, bL2); c1 = MFMA(wl21, fa1, c1);                        \
    c2 = MFMA(wl22, ba0, Z4);  c2 = MFMA(wl23, ba1, c2);                        \
    la2 = v_lk(c1 + c2);                                                        \
    c1 = MFMA(wl30, fa0, bL3); c1 = MFMA(wl31, fa1, c1);                        \
    c2 = MFMA(wl32, ba0, Z4);  c2 = MFMA(wl33, ba1, c2);                        \
    la3 = v_lk(c1 + c2);                                                        \
    /* wave-local D->A layout fix through own scratch (in-order DS, no bar) */  \
    *(int2*)&xscr[wave][n][ 0 + quad * 4] = pk4bf(la0);                         \
    *(int2*)&xscr[wave][n][16 + quad * 4] = pk4bf(la1);                         \
    *(int2*)&xscr[wave][n][32 + quad * 4] = pk4bf(la2);                         \
    *(int2*)&xscr[wave][n][48 + quad * 4] = pk4bf(la3);                         \
    if (wave < 2) {                                                             \
        *(int2*)&x2scr[wave][n][ 0 + quad * 4] = pk4bf(v_lk(la0));              \
        *(int2*)&x2scr[wave][n][16 + quad * 4] = pk4bf(v_lk(la1));              \
        *(int2*)&x2scr[wave][n][32 + quad * 4] = pk4bf(v_lk(la2));              \
        *(int2*)&x2scr[wave][n][48 + quad * 4] = pk4bf(v_lk(la3));              \
    }                                                                           \
    s16x8 xa0 = *(const s16x8*)&xscr[wave][n][quad * 8];                        \
    s16x8 xa1 = *(const s16x8*)&xscr[wave][n][32 + quad * 8];                   \
    /* out-proj + y(T) store, waves 0,1 */                                      \
    if (wave < 2) {                                                             \
        s16x8 p0 = *(const s16x8*)&x2scr[wave][n][quad * 8];                    \
        s16x8 p1 = *(const s16x8*)&x2scr[wave][n][32 + quad * 8];               \
        f32x4 po = MFMA(wo0, p0, initO);                                        \
        po = MFMA(wo1, p1, po);                                                 \
        *(f32x4*)(orow + (size_t)(T) * NF) = v_sigm(po);                        \
    }                                                                           \
    /* gates: h(T+2) = G(x(T+1), h(T+1)) */                                     \
    s16x8 ha0 = dir ? ba0 : fa0;                                                \
    s16x8 ha1 = dir ? ba1 : fa1;                                                \
    f32x4 gR = MFMA(wir0, xa0, initR);  gR = MFMA(wir1, xa1, gR);               \
    f32x4 hR = MFMA(whr0, ha0, Z4);     hR = MFMA(whr1, ha1, hR);               \
    f32x4 gZ = MFMA(wiz0, xa0, initZ);  gZ = MFMA(wiz1, xa1, gZ);               \
    f32x4 hZ = MFMA(whz0, ha0, Z4);     hZ = MFMA(whz1, ha1, hZ);               \
    f32x4 aN1 = MFMA(win0, xa0, initN1); aN1 = MFMA(win1, xa1, aN1);            \
    f32x4 aN2 = MFMA(whn0, ha0, initN2); aN2 = MFMA(whn1, ha1, aN2);            \
    hreg = gru_up(gR + hR, gZ + hZ, aN1, aN2, hreg);                            \
    *(int2*)&Hs[(HB) ^ 1][dir][n][jq] = pk4bf(hreg);                            \
    bar_lds();                                                                  \
} while (0)

    for (int t = 0; t < NS; t += 2) {
        WINDOW(0, t);
        WINDOW(1, t + 1);
    }
#undef WINDOW
    // last window stores y(NS-1); trailing h compute is harmless — no epilogue
}

extern "C" void kernel_launch(void* const* d_in, const int* in_sizes, int n_in,
                              void* d_out, int out_size, void* d_ws, size_t ws_size,
                              hipStream_t stream) {
    const float* noise = (const float*)d_in[0];
    const float* Wihf  = (const float*)d_in[1];
    const float* Whhf  = (const float*)d_in[2];
    const float* bihf  = (const float*)d_in[3];
    const float* bhhf  = (const float*)d_in[4];
    const float* Wihb  = (const float*)d_in[5];
    const float* Whhb  = (const float*)d_in[6];
    const float* bihb  = (const float*)d_in[7];
    const float* bhhb  = (const float*)d_in[8];
    const float* Wlat  = (const float*)d_in[9];
    const float* blat  = (const float*)d_in[10];
    const float* Wout  = (const float*)d_in[11];
    const float* bout  = (const float*)d_in[12];

    grugan_kernel<<<dim3(NBATCH / MROW), dim3(512), 0, stream>>>(
        noise, Wihf, Whhf, bihf, bhhf, Wihb, Whhb, bihb, bhhb,
        Wlat, blat, Wout, bout, (float*)d_out);
}